// Round 7
// baseline (189.060 us; speedup 1.0000x reference)
//
#include <hip/hip_runtime.h>

// Green-Ampt infiltration scan. B=16384 rows x T=2048 steps. Single pass.
//
// Evidence ledger:
//  R1: row-major 16B/lane stores -> 1.88x write amplification, 345us
//  R3: nontemporal -> 3.56x amplification (skips L2 combining), 1008us
//  R4: LDS transpose, full 128B lines -> 176us (~3 TB/s effective)
//  R5: 8x wave concurrency (checkpoint 2-pass) -> null (180us)
//  R6: 512B store runs + 1-block/CU -> null (177us)
// Remaining invariant: all 3 output streams are exactly 128MB apart and all
// row offsets are multiples of 8KB -> same-bank/different-DRAM-row triple
// aliasing on every flush, plus cross-block bank alignment. R7 tests bank
// decorrelation via row-rotation (per-stream +21, per-block +17), stream-
// outer flush. Everything else identical to R6.

#define GA_MIN_INF 0.1f
#define GA_EPS 1e-6f

typedef float f4 __attribute__((ext_vector_type(4)));

constexpr int ROWS   = 64;    // rows per block (= lanes)
constexpr int TSTAGE = 128;   // timesteps staged per flush (512B/row/stream)
constexpr int PITCH  = 132;   // LDS row pitch in floats (16B-aligned, odd f4)

__global__ __launch_bounds__(64, 1) void ga_kernel(
    const float* __restrict__ precip, const float* __restrict__ K,
    const float* __restrict__ psi, const float* __restrict__ dtheta,
    float* __restrict__ out, int B, int T) {
  __shared__ float s0[ROWS * PITCH];   // infiltration
  __shared__ float s1[ROWS * PITCH];   // runoff
  __shared__ float s2[ROWS * PITCH];   // cumulative F

  const int lane = threadIdx.x;
  const int rowbase = blockIdx.x * ROWS;
  const int b = rowbase + lane;

  const float Kv  = K[b];
  const float kpd = Kv * (psi[b] * dtheta[b]);

  const f4* __restrict__ pr = reinterpret_cast<const f4*>(precip + (size_t)b * T);

  const size_t BT = (size_t)B * (size_t)T;
  float* const o0 = out;
  float* const o1 = out + BT;
  float* const o2 = out + 2 * BT;

  // Flush mapping: instr g covers a rotated row pair; each row's 512B is
  // written by 32 lanes contiguously.
  const int fr = lane >> 5;          // 0..1 : which row of the pair
  const int fc = (lane & 31) * 4;    // float col 0,4,...,124
  const int rot_b = (blockIdx.x * 17) & 63;  // per-block bank decorrelation

  const int nstage = T / TSTAGE;     // 16
  const int nsb = T / 32;            // 32-step sub-batches per row (64)
  float F = 0.0f;

  f4 buf[8], nxt[8];
#pragma unroll
  for (int i = 0; i < 8; ++i) buf[i] = pr[i];

  int sb = 0;
  for (int st = 0; st < nstage; ++st) {
    // ---- compute TSTAGE steps = 4 sub-batches of 32, results into LDS ----
#pragma unroll
    for (int q = 0; q < 4; ++q) {
      if (sb + 1 < nsb) {
#pragma unroll
        for (int i = 0; i < 8; ++i) nxt[i] = pr[(sb + 1) * 8 + i];
      }
#pragma unroll
      for (int i = 0; i < 8; ++i) {
        const f4 p = buf[i];
        f4 a, r, c;
#pragma unroll
        for (int j = 0; j < 4; ++j) {
          float rF   = __builtin_amdgcn_rcpf(fmaxf(F, GA_EPS));
          float fcap = fmaxf(Kv + kpd * rF, GA_MIN_INF);
          float fact = fminf(p[j], fcap);
          r[j] = fmaxf(p[j] - fact, 0.0f);
          F += fact;
          a[j] = fact;
          c[j] = F;
        }
        const int t0 = q * 32 + i * 4;
        *reinterpret_cast<f4*>(&s0[lane * PITCH + t0]) = a;
        *reinterpret_cast<f4*>(&s1[lane * PITCH + t0]) = r;
        *reinterpret_cast<f4*>(&s2[lane * PITCH + t0]) = c;
      }
#pragma unroll
      for (int i = 0; i < 8; ++i) buf[i] = nxt[i];
      ++sb;
    }

    // ---- flush: stream-outer, row order rotated per stream and per block;
    //      rows in a pair differ as before (fr); columns stay tb..tb+512 ----
    const int tb = st * TSTAGE;
#pragma unroll
    for (int s = 0; s < 3; ++s) {
      const float* const src = (s == 0) ? s0 : (s == 1) ? s1 : s2;
      float* const dst = (s == 0) ? o0 : (s == 1) ? o1 : o2;
      const int rot = (rot_b + s * 21) & 63;
#pragma unroll
      for (int g = 0; g < 32; ++g) {
        const int r = (2 * g + fr + rot) & 63;       // rotated row (bijective)
        const size_t go = (size_t)(rowbase + r) * T + tb + fc;
        f4 v = *reinterpret_cast<const f4*>(&src[r * PITCH + fc]);
        *reinterpret_cast<f4*>(dst + go) = v;
      }
    }
  }
}

// Fallback for shapes not divisible by the tiling (not hit for 16384x2048).
__global__ void ga_fallback(
    const float* __restrict__ precip, const float* __restrict__ K,
    const float* __restrict__ psi, const float* __restrict__ dtheta,
    float* __restrict__ out, int B, int T) {
  int b = blockIdx.x * blockDim.x + threadIdx.x;
  if (b >= B) return;
  const float Kv  = K[b];
  const float kpd = Kv * (psi[b] * dtheta[b]);
  const size_t BT = (size_t)B * (size_t)T;
  float F = 0.0f;
  for (int t = 0; t < T; ++t) {
    float pv   = precip[(size_t)b * T + t];
    float rF   = __builtin_amdgcn_rcpf(fmaxf(F, GA_EPS));
    float fcap = fmaxf(Kv + kpd * rF, GA_MIN_INF);
    float fact = fminf(pv, fcap);
    float ro   = fmaxf(pv - fact, 0.0f);
    F += fact;
    out[(size_t)b * T + t] = fact;
    out[BT + (size_t)b * T + t] = ro;
    out[2 * BT + (size_t)b * T + t] = F;
  }
}

extern "C" void kernel_launch(void* const* d_in, const int* in_sizes, int n_in,
                              void* d_out, int out_size, void* d_ws, size_t ws_size,
                              hipStream_t stream) {
  const float* precip = (const float*)d_in[0];
  const float* K      = (const float*)d_in[1];
  const float* psi    = (const float*)d_in[2];
  const float* dtheta = (const float*)d_in[3];
  float* out = (float*)d_out;

  const int B = in_sizes[1];            // K has B elements
  const int T = in_sizes[0] / B;        // precip is B*T

  if ((B % ROWS) == 0 && (T % TSTAGE) == 0) {
    ga_kernel<<<B / ROWS, 64, 0, stream>>>(precip, K, psi, dtheta, out, B, T);
  } else {
    ga_fallback<<<(B + 63) / 64, 64, 0, stream>>>(precip, K, psi, dtheta, out, B, T);
  }
}

// Round 8
// 178.744 us; speedup vs baseline: 1.0577x; 1.0577x over previous
//
#include <hip/hip_runtime.h>

// Green-Ampt infiltration scan. B=16384 rows x T=2048 steps. Single pass,
// producer-consumer wave split.
//
// Evidence ledger:
//  R1: row-major 16B/lane stores -> 1.88x write amplification, 345us
//  R3: nontemporal -> 3.56x amplification (skips L2 combining), 1008us
//  R4: LDS transpose, full 128B lines -> 176us (~2.7 TB/s effective)
//  R5: 8x wave concurrency (2-pass checkpoint) -> null (pass1 masked it)
//  R6: 512B store runs -> null.  R7: bank rotation -> slightly worse.
// Diagnosis: per-wave store depth. The same wave computes the serial chain
// AND drains stores; compiler recycles store-data VGPRs -> tight vmcnt waits
// -> ~6-10 outstanding 1KB stores/CU ~= 10.5 GB/s/CU = the measured 2.7 TB/s.
// Fix: wave 0 computes into double-buffered LDS stages; waves 1-3 each drain
// one output stream with no dependence chain -> store depth x3 waves, and
// compute never stalls on vmcnt.

#define GA_MIN_INF 0.1f
#define GA_EPS 1e-6f

typedef float f4 __attribute__((ext_vector_type(4)));

constexpr int ROWS  = 64;   // rows per block (= lanes of wave 0)
constexpr int TS    = 64;   // timesteps per stage (256B per row per stream)
constexpr int PITCH = 68;   // LDS row pitch in floats (16B-aligned, banks spread)

__global__ __launch_bounds__(256, 1) void ga_pc(
    const float* __restrict__ precip, const float* __restrict__ K,
    const float* __restrict__ psi, const float* __restrict__ dtheta,
    float* __restrict__ out, int B, int T) {
  __shared__ float sb[2][3][ROWS * PITCH];   // [stage parity][stream][row*PITCH+t]

  const int tid  = threadIdx.x;
  const int wid  = tid >> 6;
  const int lane = tid & 63;
  const int rowbase = blockIdx.x * ROWS;

  const size_t BT = (size_t)B * (size_t)T;
  const int nstage = T / TS;                 // 32
  const int nsb    = T / 32;                 // 32-step sub-batches (64)

  if (wid == 0) {
    // ---------------- producer: serial recurrence into LDS stages ----------
    const int b = rowbase + lane;
    const float Kv  = K[b];
    const float kpd = Kv * (psi[b] * dtheta[b]);
    const f4* __restrict__ pr = reinterpret_cast<const f4*>(precip + (size_t)b * T);

    float F = 0.0f;
    f4 buf[8], nxt[8];
#pragma unroll
    for (int i = 0; i < 8; ++i) buf[i] = pr[i];

    int sbc = 0;
    for (int st = 0; st < nstage; ++st) {
      const int pb = st & 1;
      float* const L0 = &sb[pb][0][lane * PITCH];
      float* const L1 = &sb[pb][1][lane * PITCH];
      float* const L2 = &sb[pb][2][lane * PITCH];
#pragma unroll
      for (int q = 0; q < 2; ++q) {          // 2 x 32 steps = TS
        if (sbc + 1 < nsb) {
#pragma unroll
          for (int i = 0; i < 8; ++i) nxt[i] = pr[(sbc + 1) * 8 + i];
        }
#pragma unroll
        for (int i = 0; i < 8; ++i) {
          const f4 p = buf[i];
          f4 a, r, c;
#pragma unroll
          for (int j = 0; j < 4; ++j) {
            float rF   = __builtin_amdgcn_rcpf(fmaxf(F, GA_EPS));
            float fcap = fmaxf(Kv + kpd * rF, GA_MIN_INF);
            float fact = fminf(p[j], fcap);
            r[j] = fmaxf(p[j] - fact, 0.0f);
            F += fact;
            a[j] = fact;
            c[j] = F;
          }
          const int t0 = q * 32 + i * 4;
          *reinterpret_cast<f4*>(L0 + t0) = a;
          *reinterpret_cast<f4*>(L1 + t0) = r;
          *reinterpret_cast<f4*>(L2 + t0) = c;
        }
#pragma unroll
        for (int i = 0; i < 8; ++i) buf[i] = nxt[i];
        ++sbc;
      }
      __syncthreads();
    }
  } else {
    // ---------------- consumers: one wave per output stream ----------------
    const int s = wid - 1;
    float* const dst = out + (size_t)s * BT;
    const int fr = lane >> 4;                // 0..3 : row within quad
    const int fc = (lane & 15) * 4;          // float col 0..60

    for (int st = 0; st < nstage; ++st) {
      if (st > 0) {
        const int tb = (st - 1) * TS;
        const float* const src = &sb[(st - 1) & 1][s][0];
#pragma unroll
        for (int g = 0; g < 16; ++g) {
          const int r = g * 4 + fr;
          f4 v = *reinterpret_cast<const f4*>(&src[r * PITCH + fc]);
          *reinterpret_cast<f4*>(dst + (size_t)(rowbase + r) * T + tb + fc) = v;
        }
      }
      __syncthreads();
    }
    // drain final stage (no barrier needed; producer is done)
    {
      const int tb = (nstage - 1) * TS;
      const float* const src = &sb[(nstage - 1) & 1][s][0];
#pragma unroll
      for (int g = 0; g < 16; ++g) {
        const int r = g * 4 + fr;
        f4 v = *reinterpret_cast<const f4*>(&src[r * PITCH + fc]);
        *reinterpret_cast<f4*>(dst + (size_t)(rowbase + r) * T + tb + fc) = v;
      }
    }
  }
}

// Fallback for shapes not divisible by the tiling (not hit for 16384x2048).
__global__ void ga_fallback(
    const float* __restrict__ precip, const float* __restrict__ K,
    const float* __restrict__ psi, const float* __restrict__ dtheta,
    float* __restrict__ out, int B, int T) {
  int b = blockIdx.x * blockDim.x + threadIdx.x;
  if (b >= B) return;
  const float Kv  = K[b];
  const float kpd = Kv * (psi[b] * dtheta[b]);
  const size_t BT = (size_t)B * (size_t)T;
  float F = 0.0f;
  for (int t = 0; t < T; ++t) {
    float pv   = precip[(size_t)b * T + t];
    float rF   = __builtin_amdgcn_rcpf(fmaxf(F, GA_EPS));
    float fcap = fmaxf(Kv + kpd * rF, GA_MIN_INF);
    float fact = fminf(pv, fcap);
    float ro   = fmaxf(pv - fact, 0.0f);
    F += fact;
    out[(size_t)b * T + t] = fact;
    out[BT + (size_t)b * T + t] = ro;
    out[2 * BT + (size_t)b * T + t] = F;
  }
}

extern "C" void kernel_launch(void* const* d_in, const int* in_sizes, int n_in,
                              void* d_out, int out_size, void* d_ws, size_t ws_size,
                              hipStream_t stream) {
  const float* precip = (const float*)d_in[0];
  const float* K      = (const float*)d_in[1];
  const float* psi    = (const float*)d_in[2];
  const float* dtheta = (const float*)d_in[3];
  float* out = (float*)d_out;

  const int B = in_sizes[1];            // K has B elements
  const int T = in_sizes[0] / B;        // precip is B*T

  if ((B % ROWS) == 0 && (T % TS) == 0 && ((T / 32) % 2) == 0) {
    ga_pc<<<B / ROWS, 256, 0, stream>>>(precip, K, psi, dtheta, out, B, T);
  } else {
    ga_fallback<<<(B + 63) / 64, 64, 0, stream>>>(precip, K, psi, dtheta, out, B, T);
  }
}